// Round 3
// baseline (1234.772 us; speedup 1.0000x reference)
//
#include <hip/hip_runtime.h>

// LightGCN R6 (= R5 resubmission after container-level bench failure; no
// counter evidence of a kernel fault; source audited, defensive guards added):
//  (a) exact per-row column sort fused into sort_bucket (LDS-staged rank
//      sort): spmm's random gathers become a collective monotone sweep of
//      the bf16 table -> L2/L3 band locality. Also removes sort_bucket's
//      second global read of binned.
//  (b) bin_stage tile 12288 -> 6144 edges: LDS 141KB -> 80KB = 2 blocks/CU.
//  (c) layer-0 spmm reads x0 from uemb/iemb directly; init no longer
//      writes acc (saves one 76.8 MB write). Identical numerics.

constexpr int N_USERS_C = 100000;
constexpr int N_NODES_C = 300000;
constexpr int NNZ_C     = 9600000;
constexpr int DIM       = 64;
constexpr int TOT4      = N_NODES_C * DIM / 4;   // 4,800,000 float4
constexpr int USER4     = N_USERS_C * DIM / 4;   // 1,600,000

constexpr int BKT_SHIFT = 7;
constexpr int BKT_ROWS  = 128;
constexpr int NBKT      = (N_NODES_C + BKT_ROWS - 1) / BKT_ROWS; // 2344
constexpr int CPAD      = 16;               // ints per counter (cacheline pad)
constexpr int COL_MASK  = (1 << 19) - 1;    // col < 2^19

// RNE f32 -> bf16 pair packed into one uint (elem a in low ushort)
__device__ inline unsigned pack_bf16(float a, float b) {
    unsigned ua = __float_as_uint(a);
    unsigned ub = __float_as_uint(b);
    ua += 0x7fffu + ((ua >> 16) & 1u);
    ub += 0x7fffu + ((ub >> 16) & 1u);
    return (ua >> 16) | (ub & 0xffff0000u);
}
__device__ inline float bf_lo(unsigned w) { return __uint_as_float(w << 16); }
__device__ inline float bf_hi(unsigned w) { return __uint_as_float(w & 0xffff0000u); }

// ---------------- init: bf16 table only ----------------

__global__ void __launch_bounds__(256) init_concat_bf16(
    const float4* __restrict__ user4,
    const float4* __restrict__ item4,
    uint2*  __restrict__ xb)     // TOT4 uint2 (4 bf16 each)
{
    int i = blockIdx.x * 256 + threadIdx.x;
    if (i >= TOT4) return;
    float4 v = (i < USER4) ? user4[i] : item4[i - USER4];
    xb[i] = make_uint2(pack_bf16(v.x, v.y), pack_bf16(v.z, v.w));
}

// ---------------- bucket build ----------------

// LDS-aggregated histogram: 256 blocks x contiguous chunks.
__global__ void __launch_bounds__(1024) bucket_hist_lds(
    const int* __restrict__ rows, int* __restrict__ countsP)
{
    __shared__ int h[NBKT];
    for (int i = threadIdx.x; i < NBKT; i += 1024) h[i] = 0;
    __syncthreads();
    int per = (NNZ_C + gridDim.x - 1) / gridDim.x;
    int s = blockIdx.x * per;
    int e = min(s + per, NNZ_C);
    for (int i = s + (int)threadIdx.x; i < e; i += 1024)
        atomicAdd(&h[rows[i] >> BKT_SHIFT], 1);
    __syncthreads();
    for (int i = threadIdx.x; i < NBKT; i += 1024) {
        int c = h[i];
        if (c) atomicAdd(&countsP[i * CPAD], c);
    }
}

__global__ void __launch_bounds__(1024) bucket_scan(
    const int* __restrict__ countsP,
    int* __restrict__ bstart,        // NBKT+1
    int* __restrict__ cursorP)
{
    __shared__ int lds[1024];
    int t = threadIdx.x;
    int base = t * 3;
    int v[3]; int s = 0;
    #pragma unroll
    for (int j = 0; j < 3; ++j) {
        int idx = base + j;
        v[j] = (idx < NBKT) ? countsP[idx * CPAD] : 0;
        s += v[j];
    }
    lds[t] = s;
    __syncthreads();
    for (int off = 1; off < 1024; off <<= 1) {
        int x = (t >= off) ? lds[t - off] : 0;
        __syncthreads();
        lds[t] += x;
        __syncthreads();
    }
    int run = (t == 0) ? 0 : lds[t - 1];
    #pragma unroll
    for (int j = 0; j < 3; ++j) {
        int idx = base + j;
        if (idx < NBKT) {
            bstart[idx] = run;
            cursorP[idx * CPAD] = run;
        }
        run += v[j];
    }
    if (t == 1023) bstart[NBKT] = lds[1023];
}

// LDS-staged multisplit partition. Tile 6144 -> 80KB LDS -> 2 blocks/CU.
constexpr int STAGE_T   = 6144;            // edges per tile
constexpr int STAGE_EPT = STAGE_T / 1024;  // 6 edges per thread

__global__ void __launch_bounds__(1024) bin_stage(
    const int* __restrict__ rows, const int* __restrict__ cols,
    const float* __restrict__ vals, int* __restrict__ cursorP,
    int2* __restrict__ binned)
{
    __shared__ int2 stage[STAGE_T];              // 48 KB
    __shared__ unsigned short destB[STAGE_T];    // 12 KB
    __shared__ int hist[NBKT];                   // 9.4 KB (counts, then delta)
    __shared__ int basep[NBKT];                  // 9.4 KB (tile-local excl scan)
    __shared__ int part[16];                     // wave partials

    int t  = threadIdx.x;
    int e0 = blockIdx.x * STAGE_T;
    int cnt = min(STAGE_T, NNZ_C - e0);

    for (int i = t; i < NBKT; i += 1024) hist[i] = 0;
    __syncthreads();

    // load + local rank via atomic-return
    int  myB[STAGE_EPT];
    int  myR[STAGE_EPT];
    int2 myP[STAGE_EPT];
    #pragma unroll
    for (int j = 0; j < STAGE_EPT; ++j) {
        int i = t + j * 1024;
        myB[j] = -1;
        if (i < cnt) {
            int r = rows[e0 + i];
            int b = r >> BKT_SHIFT;
            myB[j] = b;
            myP[j] = make_int2(((r & (BKT_ROWS - 1)) << 19) | cols[e0 + i],
                               __float_as_int(vals[e0 + i]));
            myR[j] = atomicAdd(&hist[b], 1);
        }
    }
    __syncthreads();

    // exclusive scan of hist into basep (3 entries/thread, shfl wave scan)
    int idx0 = t * 3;
    int v0 = (idx0     < NBKT) ? hist[idx0]     : 0;
    int v1 = (idx0 + 1 < NBKT) ? hist[idx0 + 1] : 0;
    int v2 = (idx0 + 2 < NBKT) ? hist[idx0 + 2] : 0;
    int s  = v0 + v1 + v2;

    int lane = t & 63, wid = t >> 6;
    int x = s;
    #pragma unroll
    for (int d = 1; d < 64; d <<= 1) {
        int y = __shfl_up(x, d);
        if (lane >= d) x += y;
    }
    if (lane == 63) part[wid] = x;
    __syncthreads();
    if (wid == 0 && lane < 16) {
        int w = part[lane];
        #pragma unroll
        for (int d = 1; d < 16; d <<= 1) {
            int y = __shfl_up(w, d);
            if (lane >= d) w += y;
        }
        part[lane] = w;
    }
    __syncthreads();
    int excl = ((wid == 0) ? 0 : part[wid - 1]) + (x - s);
    if (idx0     < NBKT) basep[idx0]     = excl;          excl += v0;
    if (idx0 + 1 < NBKT) basep[idx0 + 1] = excl;          excl += v1;
    if (idx0 + 2 < NBKT) basep[idx0 + 2] = excl;
    __syncthreads();

    // reserve global ranges: hist[b] := gbase_b - lstart_b (delta)
    for (int i = t; i < NBKT; i += 1024) {
        int c = hist[i];
        hist[i] = (c > 0) ? (atomicAdd(&cursorP[i * CPAD], c) - basep[i]) : 0;
    }
    // permute payloads bucket-contiguous in LDS
    #pragma unroll
    for (int j = 0; j < STAGE_EPT; ++j) {
        if (myB[j] >= 0) {
            int q = basep[myB[j]] + myR[j];
            stage[q] = myP[j];
            destB[q] = (unsigned short)myB[j];
        }
    }
    __syncthreads();

    // coalesced-with-gaps output: runs of consecutive addresses per bucket
    #pragma unroll
    for (int j = 0; j < STAGE_EPT; ++j) {
        int p = t + j * 1024;
        if (p < cnt) {
            int b = destB[p];
            binned[hist[b] + p] = stage[p];
        }
    }
}

// per-bucket counting sort -> row-sorted CSR with cols SORTED within each
// row (exact rank sort in LDS). Single global read of binned.
constexpr int SB_CAP = 4608;   // bucket capacity (mean 4096, +8 sigma)

__global__ void __launch_bounds__(512) sort_bucket(
    const int2* __restrict__ binned,
    const int*  __restrict__ bstart,
    int2* __restrict__ binned2,
    int*  __restrict__ rowStart)    // N_NODES_C + 1
{
    __shared__ int hist[BKT_ROWS];
    __shared__ int scanb[BKT_ROWS];
    __shared__ int cur[BKT_ROWS];
    __shared__ int2 stage[SB_CAP];   // 36 KB

    int b = blockIdx.x;
    int t = threadIdx.x;
    int s = bstart[b];
    int n = bstart[b + 1] - s;

    if (t < BKT_ROWS) hist[t] = 0;
    __syncthreads();

    for (int i = t; i < n; i += 512)
        atomicAdd(&hist[binned[s + i].x >> 19], 1);
    __syncthreads();

    if (t < BKT_ROWS) scanb[t] = hist[t];
    __syncthreads();
    for (int off = 1; off < BKT_ROWS; off <<= 1) {
        int v = (t < BKT_ROWS && t >= off) ? scanb[t - off] : 0;
        __syncthreads();
        if (t < BKT_ROWS) scanb[t] += v;
        __syncthreads();
    }

    int rowBase = b << BKT_SHIFT;
    int nRows = min(BKT_ROWS, N_NODES_C - rowBase);
    if (t < BKT_ROWS) {
        int st = (t == 0) ? 0 : scanb[t - 1];
        cur[t] = st;
        if (t < nRows) rowStart[rowBase + t] = s + st;
    }
    if (b == 0 && t == 0) rowStart[N_NODES_C] = NNZ_C;
    __syncthreads();

    if (n <= SB_CAP) {
        // scatter into LDS at per-row positions
        for (int i = t; i < n; i += 512) {
            int2 p = binned[s + i];
            int rl = p.x >> 19;
            int pos = atomicAdd(&cur[rl], 1);
            if (pos < SB_CAP) stage[pos] = p;   // defensive (always true)
        }
        __syncthreads();
        // per-row exact col sort: brute-force rank, LDS broadcast reads.
        int lane = t & 63, wid = t >> 6;          // 8 waves x 16 rows
        for (int r = wid * 16; r < wid * 16 + 16; ++r) {
            int st = (r == 0) ? 0 : scanb[r - 1];
            int nr = scanb[r] - st;
            if (nr <= 0) continue;
            if (nr <= 128) {
                int i0 = lane, i1 = lane + 64;
                int2 e0 = make_int2(0, 0), e1 = make_int2(0, 0);
                if (i0 < nr) e0 = stage[st + i0];
                if (i1 < nr) e1 = stage[st + i1];
                int r0 = 0, r1 = 0;
                for (int j = 0; j < nr; ++j) {
                    int kj = stage[st + j].x;    // same addr: LDS broadcast
                    r0 += (i0 < nr) && ((kj < e0.x) || (kj == e0.x && j < i0));
                    r1 += (i1 < nr) && ((kj < e1.x) || (kj == e1.x && j < i1));
                }
                if (i0 < nr && r0 < nr) binned2[s + st + r0] = make_int2(e0.x & COL_MASK, e0.y);
                if (i1 < nr && r1 < nr) binned2[s + st + r1] = make_int2(e1.x & COL_MASK, e1.y);
            } else {
                // long row: copy out unsorted (perf-only property)
                for (int i = lane; i < nr; i += 64) {
                    int2 p = stage[st + i];
                    binned2[s + st + i] = make_int2(p.x & COL_MASK, p.y);
                }
            }
        }
    } else {
        // bucket overflow fallback: legacy direct scatter (unsorted)
        for (int i = t; i < n; i += 512) {
            int2 p = binned[s + i];
            int rl = p.x >> 19;
            int pos = atomicAdd(&cur[rl], 1);
            binned2[s + pos] = make_int2(p.x & COL_MASK, p.y);
        }
    }
}

// ---------------- pull SpMM, bf16 gathers, fused acc ----------------
// 8 lanes per row; lane q owns dims [8q, 8q+8). One uint4 = 8 bf16 per gather.
// layer0: read x0 from uemb/iemb (init never writes acc).
__global__ void __launch_bounds__(256) spmm_pull_bf16(
    const int2* __restrict__ edges,
    const int*  __restrict__ rowStart,
    const uint4* __restrict__ xb,      // bf16 table: 8 uint4 per row
    uint4* __restrict__ xb_next,       // next layer's bf16 table
    float4* __restrict__ acc,          // d_out, f32
    const float4* __restrict__ x0u,
    const float4* __restrict__ x0i,
    int layer0,
    float scale)
{
    int tid = blockIdx.x * 256 + threadIdx.x;
    int row = tid >> 3;
    if (row >= N_NODES_C) return;
    int q = tid & 7;

    int s = rowStart[row];
    int e = rowStart[row + 1];

    float y0 = 0.f, y1 = 0.f, y2 = 0.f, y3 = 0.f;
    float y4 = 0.f, y5 = 0.f, y6 = 0.f, y7 = 0.f;

    int i = s;
    for (; i + 1 < e; i += 2) {
        int2 pa = edges[i];
        int2 pb = edges[i + 1];
        uint4 ua = xb[(size_t)pa.x * 8 + q];
        uint4 ub = xb[(size_t)pb.x * 8 + q];
        float va = __int_as_float(pa.y);
        float vb = __int_as_float(pb.y);
        y0 += va * bf_lo(ua.x); y1 += va * bf_hi(ua.x);
        y2 += va * bf_lo(ua.y); y3 += va * bf_hi(ua.y);
        y4 += va * bf_lo(ua.z); y5 += va * bf_hi(ua.z);
        y6 += va * bf_lo(ua.w); y7 += va * bf_hi(ua.w);
        y0 += vb * bf_lo(ub.x); y1 += vb * bf_hi(ub.x);
        y2 += vb * bf_lo(ub.y); y3 += vb * bf_hi(ub.y);
        y4 += vb * bf_lo(ub.z); y5 += vb * bf_hi(ub.z);
        y6 += vb * bf_lo(ub.w); y7 += vb * bf_hi(ub.w);
    }
    if (i < e) {
        int2 p = edges[i];
        uint4 u = xb[(size_t)p.x * 8 + q];
        float v = __int_as_float(p.y);
        y0 += v * bf_lo(u.x); y1 += v * bf_hi(u.x);
        y2 += v * bf_lo(u.y); y3 += v * bf_hi(u.y);
        y4 += v * bf_lo(u.z); y5 += v * bf_hi(u.z);
        y6 += v * bf_lo(u.w); y7 += v * bf_hi(u.w);
    }

    // next-layer bf16 table = raw y (pre-scale)
    uint4 o;
    o.x = pack_bf16(y0, y1);
    o.y = pack_bf16(y2, y3);
    o.z = pack_bf16(y4, y5);
    o.w = pack_bf16(y6, y7);
    xb_next[(size_t)row * 8 + q] = o;

    // acc = (acc_in + y) * scale  (f32); layer0 acc_in = x0 from sources
    size_t base = (size_t)row * 16 + q * 2;
    float4 a0, a1;
    if (layer0) {
        const float4* src = (row < N_USERS_C)
            ? x0u + (size_t)row * 16 + q * 2
            : x0i + (size_t)(row - N_USERS_C) * 16 + q * 2;
        a0 = src[0];
        a1 = src[1];
    } else {
        a0 = acc[base];
        a1 = acc[base + 1];
    }
    a0.x = (a0.x + y0) * scale;
    a0.y = (a0.y + y1) * scale;
    a0.z = (a0.z + y2) * scale;
    a0.w = (a0.w + y3) * scale;
    a1.x = (a1.x + y4) * scale;
    a1.y = (a1.y + y5) * scale;
    a1.z = (a1.z + y6) * scale;
    a1.w = (a1.w + y7) * scale;
    acc[base]     = a0;
    acc[base + 1] = a1;
}

// ---------------- fallback (R0 atomic path, f32) ----------------

__global__ void __launch_bounds__(256) init_concat_f32(
    const float4* __restrict__ user4,
    const float4* __restrict__ item4,
    float4* __restrict__ emb4,
    float4* __restrict__ acc4)
{
    int i = blockIdx.x * 256 + threadIdx.x;
    if (i >= TOT4) return;
    float4 v = (i < USER4) ? user4[i] : item4[i - USER4];
    emb4[i] = v;
    acc4[i] = v;
}

__global__ void __launch_bounds__(256) spmm_scatter(
    const int*   __restrict__ rows,
    const int*   __restrict__ cols,
    const float* __restrict__ vals,
    const float* __restrict__ x,
    float*       __restrict__ y)
{
    long long tid = (long long)blockIdx.x * 256 + threadIdx.x;
    int e = (int)(tid >> 4);
    if (e >= NNZ_C) return;
    int q = (int)(tid & 15);
    int   r = rows[e];
    int   c = cols[e];
    float v = vals[e];
    float4 xv = ((const float4*)x)[c * 16 + q];
    float* yp = y + (long long)r * DIM + q * 4;
    atomicAdd(yp + 0, v * xv.x);
    atomicAdd(yp + 1, v * xv.y);
    atomicAdd(yp + 2, v * xv.z);
    atomicAdd(yp + 3, v * xv.w);
}

__global__ void __launch_bounds__(256) acc_add(
    const float4* __restrict__ nxt, float4* __restrict__ acc, float scale)
{
    int i = blockIdx.x * 256 + threadIdx.x;
    if (i >= TOT4) return;
    float4 a = acc[i];
    float4 n = nxt[i];
    a.x = (a.x + n.x) * scale;
    a.y = (a.y + n.y) * scale;
    a.z = (a.z + n.z) * scale;
    a.w = (a.w + n.w) * scale;
    acc[i] = a;
}

// ---------------- launch ----------------

extern "C" void kernel_launch(void* const* d_in, const int* in_sizes, int n_in,
                              void* d_out, int out_size, void* d_ws, size_t ws_size,
                              hipStream_t stream)
{
    const int*   rows = (const int*)  d_in[0];
    const int*   cols = (const int*)  d_in[1];
    const float* vals = (const float*)d_in[2];
    const float* uemb = (const float*)d_in[3];
    const float* iemb = (const float*)d_in[4];
    float*       out  = (float*)d_out;

    const size_t embBytes   = (size_t)N_NODES_C * DIM * sizeof(float);   // 76.8 MB
    const size_t bfBytes    = (size_t)N_NODES_C * DIM * 2;               // 38.4 MB
    const size_t edgeBytes  = (size_t)NNZ_C * sizeof(int2);              // 76.8 MB
    const size_t padBytes   = (size_t)NBKT * CPAD * sizeof(int);         // 150 KB
    const size_t rsBytes    = (size_t)(N_NODES_C + 1) * sizeof(int);     // 1.2 MB

    char* w = (char*)d_ws;
    size_t off = 0;
    unsigned* xbf0   = (unsigned*)(w + off); off += bfBytes;
    unsigned* xbf1   = (unsigned*)(w + off); off += bfBytes;
    int2*  binned    = (int2*) (w + off); off += edgeBytes;
    int2*  binned2   = (int2*) (w + off); off += edgeBytes;
    int*   rowStart  = (int*)  (w + off); off += rsBytes;
    int*   countsP   = (int*)  (w + off); off += padBytes;
    int*   cursorP   = (int*)  (w + off); off += padBytes;
    int*   bstart    = (int*)  (w + off); off += (size_t)(NBKT + 1) * sizeof(int) + 4096;
    const size_t needed = off;   // ~232 MB

    const int gridE    = (TOT4 + 255) / 256;
    const int gridPull = (N_NODES_C * 8) / 256;   // 9375
    const int gridBin  = (NNZ_C + STAGE_T - 1) / STAGE_T;   // 1563

    if (ws_size >= needed) {
        init_concat_bf16<<<gridE, 256, 0, stream>>>(
            (const float4*)uemb, (const float4*)iemb, (uint2*)xbf0);

        hipMemsetAsync(countsP, 0, padBytes, stream);
        bucket_hist_lds<<<256, 1024, 0, stream>>>(rows, countsP);
        bucket_scan<<<1, 1024, 0, stream>>>(countsP, bstart, cursorP);
        bin_stage<<<gridBin, 1024, 0, stream>>>(rows, cols, vals, cursorP, binned);
        sort_bucket<<<NBKT, 512, 0, stream>>>(binned, bstart, binned2, rowStart);

        unsigned* cur = xbf0;
        unsigned* nxt = xbf1;
        for (int layer = 0; layer < 3; ++layer) {
            float scale = (layer == 2) ? 0.25f : 1.0f;
            spmm_pull_bf16<<<gridPull, 256, 0, stream>>>(
                binned2, rowStart, (const uint4*)cur, (uint4*)nxt,
                (float4*)out, (const float4*)uemb, (const float4*)iemb,
                (layer == 0) ? 1 : 0, scale);
            unsigned* t = cur; cur = nxt; nxt = t;
        }
    } else {
        // fallback: atomic scatter path (needs only 2*embBytes)
        float* buf0 = (float*)d_ws;
        float* buf1 = (float*)((char*)d_ws + embBytes);
        init_concat_f32<<<gridE, 256, 0, stream>>>(
            (const float4*)uemb, (const float4*)iemb, (float4*)buf0, (float4*)out);
        const long long sThreads = (long long)NNZ_C * 16;
        const int gridS = (int)((sThreads + 255) / 256);
        float* cur = buf0;
        float* nxt = buf1;
        for (int layer = 0; layer < 3; ++layer) {
            hipMemsetAsync(nxt, 0, embBytes, stream);
            spmm_scatter<<<gridS, 256, 0, stream>>>(rows, cols, vals, cur, nxt);
            float scale = (layer == 2) ? 0.25f : 1.0f;
            acc_add<<<gridE, 256, 0, stream>>>((const float4*)nxt, (float4*)out, scale);
            float* t = cur; cur = nxt; nxt = t;
        }
    }
}

// Round 4
// 1038.407 us; speedup vs baseline: 1.1891x; 1.1891x over previous
//
#include <hip/hip_runtime.h>

// LightGCN R7: fix bin_stage write amplification via COARSE buckets.
// R6 evidence: amp = f(buckets per tile). 2344 buckets x 6144-edge tile ->
// 2.6-edge runs (21B) -> 3.3x write amp (255MB/77MB), 226us. Col-sort in
// sort_bucket refuted (VALU-bound, 85% busy, 2.76M bank conflicts, +226us).
//  - BKT_SHIFT 7 -> 9: 512-row buckets, NBKT=586. Runs 10.5 edges (84B),
//    amp ~1.5. destB/hist/basep shrink; tile 6144 @ 64.7KB = 2 blocks/CU.
//  - sort_bucket: 586 blocks x 1024 thr, plain two-pass counting sort over
//    512 rows (no col sort). One block per contiguous segment -> no amp.
//  - spmm unchanged from R4/R6 (layer0 reads x0 from uemb/iemb; init
//    writes only the bf16 table).

constexpr int N_USERS_C = 100000;
constexpr int N_NODES_C = 300000;
constexpr int NNZ_C     = 9600000;
constexpr int DIM       = 64;
constexpr int TOT4      = N_NODES_C * DIM / 4;   // 4,800,000 float4
constexpr int USER4     = N_USERS_C * DIM / 4;   // 1,600,000

constexpr int BKT_SHIFT = 9;
constexpr int BKT_ROWS  = 512;
constexpr int NBKT      = (N_NODES_C + BKT_ROWS - 1) / BKT_ROWS; // 586
constexpr int CPAD      = 16;               // ints per counter (cacheline pad)
constexpr int COL_MASK  = (1 << 19) - 1;    // col < 2^19; rl in bits 19..27

// RNE f32 -> bf16 pair packed into one uint (elem a in low ushort)
__device__ inline unsigned pack_bf16(float a, float b) {
    unsigned ua = __float_as_uint(a);
    unsigned ub = __float_as_uint(b);
    ua += 0x7fffu + ((ua >> 16) & 1u);
    ub += 0x7fffu + ((ub >> 16) & 1u);
    return (ua >> 16) | (ub & 0xffff0000u);
}
__device__ inline float bf_lo(unsigned w) { return __uint_as_float(w << 16); }
__device__ inline float bf_hi(unsigned w) { return __uint_as_float(w & 0xffff0000u); }

// ---------------- init: bf16 table only ----------------

__global__ void __launch_bounds__(256) init_concat_bf16(
    const float4* __restrict__ user4,
    const float4* __restrict__ item4,
    uint2*  __restrict__ xb)     // TOT4 uint2 (4 bf16 each)
{
    int i = blockIdx.x * 256 + threadIdx.x;
    if (i >= TOT4) return;
    float4 v = (i < USER4) ? user4[i] : item4[i - USER4];
    xb[i] = make_uint2(pack_bf16(v.x, v.y), pack_bf16(v.z, v.w));
}

// ---------------- bucket build ----------------

// LDS-aggregated histogram: 256 blocks x contiguous chunks.
__global__ void __launch_bounds__(1024) bucket_hist_lds(
    const int* __restrict__ rows, int* __restrict__ countsP)
{
    __shared__ int h[NBKT];
    for (int i = threadIdx.x; i < NBKT; i += 1024) h[i] = 0;
    __syncthreads();
    int per = (NNZ_C + gridDim.x - 1) / gridDim.x;
    int s = blockIdx.x * per;
    int e = min(s + per, NNZ_C);
    for (int i = s + (int)threadIdx.x; i < e; i += 1024)
        atomicAdd(&h[rows[i] >> BKT_SHIFT], 1);
    __syncthreads();
    for (int i = threadIdx.x; i < NBKT; i += 1024) {
        int c = h[i];
        if (c) atomicAdd(&countsP[i * CPAD], c);
    }
}

// NBKT (586) <= 1024: one bucket per thread, single Hillis-Steele scan.
__global__ void __launch_bounds__(1024) bucket_scan(
    const int* __restrict__ countsP,
    int* __restrict__ bstart,        // NBKT+1
    int* __restrict__ cursorP)
{
    __shared__ int lds[1024];
    int t = threadIdx.x;
    int v = (t < NBKT) ? countsP[t * CPAD] : 0;
    lds[t] = v;
    __syncthreads();
    for (int off = 1; off < 1024; off <<= 1) {
        int x = (t >= off) ? lds[t - off] : 0;
        __syncthreads();
        lds[t] += x;
        __syncthreads();
    }
    int excl = lds[t] - v;
    if (t < NBKT) {
        bstart[t] = excl;
        cursorP[t * CPAD] = excl;
    }
    if (t == 1023) bstart[NBKT] = lds[1023];
}

// LDS-staged multisplit partition into 586 coarse buckets.
constexpr int STAGE_T   = 6144;            // edges per tile
constexpr int STAGE_EPT = STAGE_T / 1024;  // 6 edges per thread

__global__ void __launch_bounds__(1024) bin_stage(
    const int* __restrict__ rows, const int* __restrict__ cols,
    const float* __restrict__ vals, int* __restrict__ cursorP,
    int2* __restrict__ binned)
{
    __shared__ int2 stage[STAGE_T];              // 48 KB
    __shared__ unsigned short destB[STAGE_T];    // 12 KB
    __shared__ int hist[NBKT];                   // 2.3 KB (counts, then delta)
    __shared__ int basep[NBKT];                  // 2.3 KB (tile-local excl scan)
    __shared__ int part[16];                     // wave partials

    int t  = threadIdx.x;
    int e0 = blockIdx.x * STAGE_T;
    int cnt = min(STAGE_T, NNZ_C - e0);

    for (int i = t; i < NBKT; i += 1024) hist[i] = 0;
    __syncthreads();

    // load + local rank via atomic-return
    int  myB[STAGE_EPT];
    int  myR[STAGE_EPT];
    int2 myP[STAGE_EPT];
    #pragma unroll
    for (int j = 0; j < STAGE_EPT; ++j) {
        int i = t + j * 1024;
        myB[j] = -1;
        if (i < cnt) {
            int r = rows[e0 + i];
            int b = r >> BKT_SHIFT;
            myB[j] = b;
            myP[j] = make_int2(((r & (BKT_ROWS - 1)) << 19) | cols[e0 + i],
                               __float_as_int(vals[e0 + i]));
            myR[j] = atomicAdd(&hist[b], 1);
        }
    }
    __syncthreads();

    // exclusive scan of hist into basep (1 entry/thread, shfl wave scan)
    int v0 = (t < NBKT) ? hist[t] : 0;

    int lane = t & 63, wid = t >> 6;
    int x = v0;
    #pragma unroll
    for (int d = 1; d < 64; d <<= 1) {
        int y = __shfl_up(x, d);
        if (lane >= d) x += y;
    }
    if (lane == 63) part[wid] = x;
    __syncthreads();
    if (wid == 0 && lane < 16) {
        int w = part[lane];
        #pragma unroll
        for (int d = 1; d < 16; d <<= 1) {
            int y = __shfl_up(w, d);
            if (lane >= d) w += y;
        }
        part[lane] = w;
    }
    __syncthreads();
    int excl = ((wid == 0) ? 0 : part[wid - 1]) + (x - v0);
    if (t < NBKT) basep[t] = excl;
    __syncthreads();

    // reserve global ranges: hist[b] := gbase_b - lstart_b (delta)
    for (int i = t; i < NBKT; i += 1024) {
        int c = hist[i];
        hist[i] = (c > 0) ? (atomicAdd(&cursorP[i * CPAD], c) - basep[i]) : 0;
    }
    // permute payloads bucket-contiguous in LDS
    #pragma unroll
    for (int j = 0; j < STAGE_EPT; ++j) {
        if (myB[j] >= 0) {
            int q = basep[myB[j]] + myR[j];
            stage[q] = myP[j];
            destB[q] = (unsigned short)myB[j];
        }
    }
    __syncthreads();

    // coalesced-with-gaps output: ~10-edge (84B) runs per bucket
    #pragma unroll
    for (int j = 0; j < STAGE_EPT; ++j) {
        int p = t + j * 1024;
        if (p < cnt) {
            int b = destB[p];
            binned[hist[b] + p] = stage[p];
        }
    }
}

// per-coarse-bucket counting sort -> final CSR (binned2) + rowStart.
// One block per 512-row segment (~131 KB of edges): pass1 hist, pass2
// scatter. Second pass and all writes are L2-local -> no write amp.
__global__ void __launch_bounds__(1024) sort_bucket(
    const int2* __restrict__ binned,
    const int*  __restrict__ bstart,
    int2* __restrict__ binned2,
    int*  __restrict__ rowStart)    // N_NODES_C + 1
{
    __shared__ int hist[BKT_ROWS];
    __shared__ int scanb[BKT_ROWS];
    __shared__ int cur[BKT_ROWS];

    int b = blockIdx.x;
    int t = threadIdx.x;
    int s = bstart[b];
    int n = bstart[b + 1] - s;

    if (t < BKT_ROWS) hist[t] = 0;
    __syncthreads();

    for (int i = t; i < n; i += 1024)
        atomicAdd(&hist[binned[s + i].x >> 19], 1);
    __syncthreads();

    if (t < BKT_ROWS) scanb[t] = hist[t];
    __syncthreads();
    for (int off = 1; off < BKT_ROWS; off <<= 1) {
        int v = (t < BKT_ROWS && t >= off) ? scanb[t - off] : 0;
        __syncthreads();
        if (t < BKT_ROWS) scanb[t] += v;
        __syncthreads();
    }

    int rowBase = b << BKT_SHIFT;
    int nRows = min(BKT_ROWS, N_NODES_C - rowBase);
    if (t < BKT_ROWS) {
        int st = (t == 0) ? 0 : scanb[t - 1];
        cur[t] = st;
        if (t < nRows) rowStart[rowBase + t] = s + st;
    }
    if (b == 0 && t == 0) rowStart[N_NODES_C] = NNZ_C;
    __syncthreads();

    for (int i = t; i < n; i += 1024) {
        int2 p = binned[s + i];
        int rl = p.x >> 19;
        int pos = atomicAdd(&cur[rl], 1);
        binned2[s + pos] = make_int2(p.x & COL_MASK, p.y);
    }
}

// ---------------- pull SpMM, bf16 gathers, fused acc ----------------
// 8 lanes per row; lane q owns dims [8q, 8q+8). One uint4 = 8 bf16 per gather.
// layer0: read x0 from uemb/iemb (init never writes acc).
__global__ void __launch_bounds__(256) spmm_pull_bf16(
    const int2* __restrict__ edges,
    const int*  __restrict__ rowStart,
    const uint4* __restrict__ xb,      // bf16 table: 8 uint4 per row
    uint4* __restrict__ xb_next,       // next layer's bf16 table
    float4* __restrict__ acc,          // d_out, f32
    const float4* __restrict__ x0u,
    const float4* __restrict__ x0i,
    int layer0,
    float scale)
{
    int tid = blockIdx.x * 256 + threadIdx.x;
    int row = tid >> 3;
    if (row >= N_NODES_C) return;
    int q = tid & 7;

    int s = rowStart[row];
    int e = rowStart[row + 1];

    float y0 = 0.f, y1 = 0.f, y2 = 0.f, y3 = 0.f;
    float y4 = 0.f, y5 = 0.f, y6 = 0.f, y7 = 0.f;

    int i = s;
    for (; i + 1 < e; i += 2) {
        int2 pa = edges[i];
        int2 pb = edges[i + 1];
        uint4 ua = xb[(size_t)pa.x * 8 + q];
        uint4 ub = xb[(size_t)pb.x * 8 + q];
        float va = __int_as_float(pa.y);
        float vb = __int_as_float(pb.y);
        y0 += va * bf_lo(ua.x); y1 += va * bf_hi(ua.x);
        y2 += va * bf_lo(ua.y); y3 += va * bf_hi(ua.y);
        y4 += va * bf_lo(ua.z); y5 += va * bf_hi(ua.z);
        y6 += va * bf_lo(ua.w); y7 += va * bf_hi(ua.w);
        y0 += vb * bf_lo(ub.x); y1 += vb * bf_hi(ub.x);
        y2 += vb * bf_lo(ub.y); y3 += vb * bf_hi(ub.y);
        y4 += vb * bf_lo(ub.z); y5 += vb * bf_hi(ub.z);
        y6 += vb * bf_lo(ub.w); y7 += vb * bf_hi(ub.w);
    }
    if (i < e) {
        int2 p = edges[i];
        uint4 u = xb[(size_t)p.x * 8 + q];
        float v = __int_as_float(p.y);
        y0 += v * bf_lo(u.x); y1 += v * bf_hi(u.x);
        y2 += v * bf_lo(u.y); y3 += v * bf_hi(u.y);
        y4 += v * bf_lo(u.z); y5 += v * bf_hi(u.z);
        y6 += v * bf_lo(u.w); y7 += v * bf_hi(u.w);
    }

    // next-layer bf16 table = raw y (pre-scale)
    uint4 o;
    o.x = pack_bf16(y0, y1);
    o.y = pack_bf16(y2, y3);
    o.z = pack_bf16(y4, y5);
    o.w = pack_bf16(y6, y7);
    xb_next[(size_t)row * 8 + q] = o;

    // acc = (acc_in + y) * scale  (f32); layer0 acc_in = x0 from sources
    size_t base = (size_t)row * 16 + q * 2;
    float4 a0, a1;
    if (layer0) {
        const float4* src = (row < N_USERS_C)
            ? x0u + (size_t)row * 16 + q * 2
            : x0i + (size_t)(row - N_USERS_C) * 16 + q * 2;
        a0 = src[0];
        a1 = src[1];
    } else {
        a0 = acc[base];
        a1 = acc[base + 1];
    }
    a0.x = (a0.x + y0) * scale;
    a0.y = (a0.y + y1) * scale;
    a0.z = (a0.z + y2) * scale;
    a0.w = (a0.w + y3) * scale;
    a1.x = (a1.x + y4) * scale;
    a1.y = (a1.y + y5) * scale;
    a1.z = (a1.z + y6) * scale;
    a1.w = (a1.w + y7) * scale;
    acc[base]     = a0;
    acc[base + 1] = a1;
}

// ---------------- fallback (R0 atomic path, f32) ----------------

__global__ void __launch_bounds__(256) init_concat_f32(
    const float4* __restrict__ user4,
    const float4* __restrict__ item4,
    float4* __restrict__ emb4,
    float4* __restrict__ acc4)
{
    int i = blockIdx.x * 256 + threadIdx.x;
    if (i >= TOT4) return;
    float4 v = (i < USER4) ? user4[i] : item4[i - USER4];
    emb4[i] = v;
    acc4[i] = v;
}

__global__ void __launch_bounds__(256) spmm_scatter(
    const int*   __restrict__ rows,
    const int*   __restrict__ cols,
    const float* __restrict__ vals,
    const float* __restrict__ x,
    float*       __restrict__ y)
{
    long long tid = (long long)blockIdx.x * 256 + threadIdx.x;
    int e = (int)(tid >> 4);
    if (e >= NNZ_C) return;
    int q = (int)(tid & 15);
    int   r = rows[e];
    int   c = cols[e];
    float v = vals[e];
    float4 xv = ((const float4*)x)[c * 16 + q];
    float* yp = y + (long long)r * DIM + q * 4;
    atomicAdd(yp + 0, v * xv.x);
    atomicAdd(yp + 1, v * xv.y);
    atomicAdd(yp + 2, v * xv.z);
    atomicAdd(yp + 3, v * xv.w);
}

__global__ void __launch_bounds__(256) acc_add(
    const float4* __restrict__ nxt, float4* __restrict__ acc, float scale)
{
    int i = blockIdx.x * 256 + threadIdx.x;
    if (i >= TOT4) return;
    float4 a = acc[i];
    float4 n = nxt[i];
    a.x = (a.x + n.x) * scale;
    a.y = (a.y + n.y) * scale;
    a.z = (a.z + n.z) * scale;
    a.w = (a.w + n.w) * scale;
    acc[i] = a;
}

// ---------------- launch ----------------

extern "C" void kernel_launch(void* const* d_in, const int* in_sizes, int n_in,
                              void* d_out, int out_size, void* d_ws, size_t ws_size,
                              hipStream_t stream)
{
    const int*   rows = (const int*)  d_in[0];
    const int*   cols = (const int*)  d_in[1];
    const float* vals = (const float*)d_in[2];
    const float* uemb = (const float*)d_in[3];
    const float* iemb = (const float*)d_in[4];
    float*       out  = (float*)d_out;

    const size_t embBytes   = (size_t)N_NODES_C * DIM * sizeof(float);   // 76.8 MB
    const size_t bfBytes    = (size_t)N_NODES_C * DIM * 2;               // 38.4 MB
    const size_t edgeBytes  = (size_t)NNZ_C * sizeof(int2);              // 76.8 MB
    const size_t padBytes   = (size_t)NBKT * CPAD * sizeof(int);         // 37.5 KB
    const size_t rsBytes    = (size_t)(N_NODES_C + 1) * sizeof(int);     // 1.2 MB

    char* w = (char*)d_ws;
    size_t off = 0;
    unsigned* xbf0   = (unsigned*)(w + off); off += bfBytes;
    unsigned* xbf1   = (unsigned*)(w + off); off += bfBytes;
    int2*  binned    = (int2*) (w + off); off += edgeBytes;
    int2*  binned2   = (int2*) (w + off); off += edgeBytes;
    int*   rowStart  = (int*)  (w + off); off += rsBytes;
    int*   countsP   = (int*)  (w + off); off += padBytes;
    int*   cursorP   = (int*)  (w + off); off += padBytes;
    int*   bstart    = (int*)  (w + off); off += (size_t)(NBKT + 1) * sizeof(int) + 4096;
    const size_t needed = off;   // ~232 MB

    const int gridE    = (TOT4 + 255) / 256;
    const int gridPull = (N_NODES_C * 8) / 256;   // 9375
    const int gridBin  = (NNZ_C + STAGE_T - 1) / STAGE_T;   // 1563

    if (ws_size >= needed) {
        init_concat_bf16<<<gridE, 256, 0, stream>>>(
            (const float4*)uemb, (const float4*)iemb, (uint2*)xbf0);

        hipMemsetAsync(countsP, 0, padBytes, stream);
        bucket_hist_lds<<<256, 1024, 0, stream>>>(rows, countsP);
        bucket_scan<<<1, 1024, 0, stream>>>(countsP, bstart, cursorP);
        bin_stage<<<gridBin, 1024, 0, stream>>>(rows, cols, vals, cursorP, binned);
        sort_bucket<<<NBKT, 1024, 0, stream>>>(binned, bstart, binned2, rowStart);

        unsigned* cur = xbf0;
        unsigned* nxt = xbf1;
        for (int layer = 0; layer < 3; ++layer) {
            float scale = (layer == 2) ? 0.25f : 1.0f;
            spmm_pull_bf16<<<gridPull, 256, 0, stream>>>(
                binned2, rowStart, (const uint4*)cur, (uint4*)nxt,
                (float4*)out, (const float4*)uemb, (const float4*)iemb,
                (layer == 0) ? 1 : 0, scale);
            unsigned* t = cur; cur = nxt; nxt = t;
        }
    } else {
        // fallback: atomic scatter path (needs only 2*embBytes)
        float* buf0 = (float*)d_ws;
        float* buf1 = (float*)((char*)d_ws + embBytes);
        init_concat_f32<<<gridE, 256, 0, stream>>>(
            (const float4*)uemb, (const float4*)iemb, (float4*)buf0, (float4*)out);
        const long long sThreads = (long long)NNZ_C * 16;
        const int gridS = (int)((sThreads + 255) / 256);
        float* cur = buf0;
        float* nxt = buf1;
        for (int layer = 0; layer < 3; ++layer) {
            hipMemsetAsync(nxt, 0, embBytes, stream);
            spmm_scatter<<<gridS, 256, 0, stream>>>(rows, cols, vals, cur, nxt);
            float scale = (layer == 2) ? 0.25f : 1.0f;
            acc_add<<<gridE, 256, 0, stream>>>((const float4*)nxt, (float4*)out, scale);
            float* t = cur; cur = nxt; nxt = t;
        }
    }
}